// Round 2
// baseline (10779.259 us; speedup 1.0000x reference)
//
#include <hip/hip_runtime.h>
#include <stdint.h>

#define DMODEL 768
#define DINNER 1536
#define NSTATE 16
#define KCONV 4
#define RRANK 48
#define NLAYER 8
#define BLL 2048   // B*L tokens
#define LSEQ 1024
#define BATCH 2

__device__ __forceinline__ float bf2f(ushort u) {
  union { float f; uint32_t i; } v; v.i = ((uint32_t)u) << 16; return v.f;
}
__device__ __forceinline__ ushort f2bf(float f) {
  uint32_t x = __float_as_uint(f);
  uint32_t r = (x + 0x7fffu + ((x >> 16) & 1u)) >> 16;  // round-nearest-even
  return (ushort)r;
}
// flag-switched input loader: fp32flag=1 -> fp32 data, 0 -> bf16 data
__device__ __forceinline__ float ldf(const void* p, size_t i, int fp32flag) {
  return fp32flag ? ((const float*)p)[i] : bf2f(((const ushort*)p)[i]);
}

typedef __attribute__((ext_vector_type(8))) __bf16 bf16x8;
typedef __attribute__((ext_vector_type(4))) float f32x4;

// ---------------- dtype probe: is input data fp32 or bf16? ----------------
// Examine low ushort of first 4096 32-bit words of the embedding table.
// bf16 data: low ushort is a genuine small bf16 -> ~100% "sane".
// fp32 data: low ushort is random mantissa bits -> ~31% "sane".
__global__ __launch_bounds__(256) void probe_kernel(const void* emb, int* flag) {
  int tid = threadIdx.x;
  int good = 0;
  for (int i = tid; i < 4096; i += 256) {
    float v = bf2f(((const ushort*)emb)[2 * i]);  // little-endian low half
    float a = fabsf(v);
    if (v == 0.f || (a >= 1e-8f && a <= 1e4f)) good++;
  }
  __shared__ int red[4];
  #pragma unroll
  for (int off = 32; off > 0; off >>= 1) good += __shfl_down(good, off, 64);
  if ((tid & 63) == 0) red[tid >> 6] = good;
  __syncthreads();
  if (tid == 0) {
    int g = red[0] + red[1] + red[2] + red[3];
    *flag = (g < 2867) ? 1 : 0;   // <70% sane => fp32 inputs
  }
}

// ---------------- weight convert: input (either dtype) -> bf16 ws copy ----------------
__global__ __launch_bounds__(256) void wcvt_kernel(const void* src, size_t elem_off,
                                                   ushort* __restrict__ dst,
                                                   const int* __restrict__ flag) {
  int f = *flag;
  size_t i = (size_t)blockIdx.x * 256 + threadIdx.x;
  dst[i] = f2bf(ldf(src, elem_off + i, f));
}

// ---------------- embedding lookup -> fp32 residual ----------------
__global__ __launch_bounds__(256) void embed_kernel(
    const int* __restrict__ ids, const void* __restrict__ emb,
    float* __restrict__ res, const int* __restrict__ flag) {
  int f = *flag;
  int idx = blockIdx.x * 256 + threadIdx.x;           // BLL*DMODEL
  int m = idx / DMODEL, c = idx % DMODEL;
  res[idx] = ldf(emb, (size_t)ids[m] * DMODEL + c, f);
}

// ---------------- RMSNorm: res(f32) -> h(bf16) or final out (per flag) ----------------
__global__ __launch_bounds__(256) void rms_kernel(
    const float* __restrict__ res, const void* __restrict__ w, size_t w_off,
    void* __restrict__ out, const int* __restrict__ flag, int final_store) {
  int f = *flag;
  int m = blockIdx.x;
  const float* r = res + (size_t)m * DMODEL;
  float ss = 0.f;
  for (int i = threadIdx.x; i < DMODEL; i += 256) { float v = r[i]; ss += v * v; }
  #pragma unroll
  for (int off = 32; off > 0; off >>= 1) ss += __shfl_down(ss, off, 64);
  __shared__ float red[4];
  if ((threadIdx.x & 63) == 0) red[threadIdx.x >> 6] = ss;
  __syncthreads();
  float scale = rsqrtf((red[0] + red[1] + red[2] + red[3]) / (float)DMODEL + 1e-5f);
  for (int i = threadIdx.x; i < DMODEL; i += 256) {
    float v = r[i] * scale * ldf(w, w_off + i, f);
    size_t o = (size_t)m * DMODEL + i;
    if (final_store) {
      if (f) ((float*)out)[o] = v; else ((ushort*)out)[o] = f2bf(v);
    } else {
      ((ushort*)out)[o] = f2bf(v);
    }
  }
}

// ---------------- GEMM: C[M,N] (+)= A[M,K] * W[N,K]^T ----------------
// A,W bf16 row-major K-contiguous. 64x64 tile, 4 waves; MFMA 16x16x32 bf16.
//   A frag: m=lane&15, k=quad*8+j (contiguous -> 16B load)
//   B frag: n=lane&15, k=quad*8+j
//   D:      col=lane&15, row=quad*4+reg
// OUT_MODE: 0 = f32 store, 2 = f32 accumulate (+=)
template <int OUT_MODE>
__global__ __launch_bounds__(256) void gemm_nt(
    const ushort* __restrict__ A, const ushort* __restrict__ W,
    float* __restrict__ Cout, int M, int N, int K) {
  int wave = threadIdx.x >> 6, lane = threadIdx.x & 63;
  int quad = lane >> 4, lq = lane & 15;
  int bm = blockIdx.y * 64, bn = blockIdx.x * 64;
  int row = bm + wave * 16 + lq;
  const ushort* Ap = A + (size_t)row * K + quad * 8;
  f32x4 acc[4] = {};
  for (int kk = 0; kk < K; kk += 32) {
    bf16x8 af = *(const bf16x8*)(Ap + kk);
    #pragma unroll
    for (int t = 0; t < 4; ++t) {
      int col = bn + t * 16 + lq;
      bf16x8 bfv = {};
      if (col < N) bfv = *(const bf16x8*)(W + (size_t)col * K + kk + quad * 8);
      acc[t] = __builtin_amdgcn_mfma_f32_16x16x32_bf16(af, bfv, acc[t], 0, 0, 0);
    }
  }
  #pragma unroll
  for (int t = 0; t < 4; ++t) {
    int col = bn + t * 16 + lq;
    if (col >= N) continue;
    #pragma unroll
    for (int r = 0; r < 4; ++r) {
      int rr = bm + wave * 16 + quad * 4 + r;
      size_t off = (size_t)rr * N + col;
      if (OUT_MODE == 0) Cout[off] = acc[t][r];
      else               Cout[off] += acc[t][r];
    }
  }
}

// ---------------- causal depthwise conv (K=4) + SiLU ----------------
// xi = xz columns [0, DINNER), fp32, row stride 2*DINNER.
__global__ __launch_bounds__(256) void conv_kernel(
    const float* __restrict__ xz, const void* __restrict__ cw, size_t cw_off,
    const void* __restrict__ cb, size_t cb_off,
    ushort* __restrict__ xcb, float* __restrict__ xcf,
    const int* __restrict__ flag) {
  int f = *flag;
  int idx = blockIdx.x * 256 + threadIdx.x;           // BLL*DINNER
  int d = idx % DINNER, m = idx / DINNER;
  int l = m & (LSEQ - 1);
  float s = ldf(cb, cb_off + d, f);
  #pragma unroll
  for (int k = 0; k < KCONV; ++k) {
    int ls = l - (KCONV - 1) + k;
    if (ls >= 0)
      s = fmaf(xz[(size_t)(m - (KCONV - 1) + k) * (2 * DINNER) + d],
               ldf(cw, cw_off + d * KCONV + k, f), s);
  }
  float v = s / (1.f + __expf(-s));   // silu
  xcb[idx] = f2bf(v);
  xcf[idx] = v;
}

// ---------------- dt = softplus(dt_raw @ dt_proj_w^T + dt_proj_b) ----------------
__global__ __launch_bounds__(256) void dtproj_kernel(
    const float* __restrict__ dbl, const void* __restrict__ dtw, size_t dtw_off,
    const void* __restrict__ dtb, size_t dtb_off,
    float* __restrict__ dt, const int* __restrict__ flag) {
  int f = *flag;
  int idx = blockIdx.x * 256 + threadIdx.x;           // BLL*DINNER
  int d = idx % DINNER, m = idx / DINNER;
  const float* rowp = dbl + (size_t)m * 80;
  float s = ldf(dtb, dtb_off + d, f);
  #pragma unroll 8
  for (int r = 0; r < RRANK; ++r)
    s = fmaf(rowp[r], ldf(dtw, dtw_off + (size_t)d * RRANK + r, f), s);
  dt[idx] = (s > 20.f) ? s : log1pf(__expf(s));
}

// ---------------- selective scan + D skip + silu(z) gating ----------------
// thread = (b, d, n): n = tid&15, 16 d-channels per block; h in register.
__global__ __launch_bounds__(256) void scan_kernel(
    const float* __restrict__ dt, const float* __restrict__ xcf,
    const float* __restrict__ dbl, const float* __restrict__ xz,
    const void* __restrict__ A_log, size_t al_off,
    const void* __restrict__ Dp, size_t dp_off,
    ushort* __restrict__ yg, const int* __restrict__ flag) {
  int f = *flag;
  int b = blockIdx.x / (DINNER / 16);
  int dblk = blockIdx.x % (DINNER / 16);
  int n = threadIdx.x & 15;
  int d = dblk * 16 + (threadIdx.x >> 4);
  float Ac = -__expf(ldf(A_log, al_off + (size_t)d * NSTATE + n, f));
  float Dd = ldf(Dp, dp_off + d, f);
  float h = 0.f;
  for (int l = 0; l < LSEQ; ++l) {
    int m = b * LSEQ + l;
    float dtv = dt[(size_t)m * DINNER + d];
    float u = xcf[(size_t)m * DINNER + d];
    float Bv = dbl[(size_t)m * 80 + 48 + n];
    float Cv = dbl[(size_t)m * 80 + 64 + n];
    float a = __expf(dtv * Ac);
    h = fmaf(a, h, dtv * u * Bv);
    float p = h * Cv;
    p += __shfl_xor(p, 8, 16);
    p += __shfl_xor(p, 4, 16);
    p += __shfl_xor(p, 2, 16);
    p += __shfl_xor(p, 1, 16);
    if (n == 0) {
      float y = p + u * Dd;
      float zv = xz[(size_t)m * (2 * DINNER) + DINNER + d];
      float g = zv / (1.f + __expf(-zv));             // silu(z)
      yg[(size_t)m * DINNER + d] = f2bf(y * g);
    }
  }
}

extern "C" void kernel_launch(void* const* d_in, const int* in_sizes, int n_in,
                              void* d_out, int out_size, void* d_ws, size_t ws_size,
                              hipStream_t stream) {
  const int*  ids   = (const int*)d_in[0];
  const void* emb   = d_in[1];
  const void* inw   = d_in[2];
  const void* cw    = d_in[3];
  const void* cb    = d_in[4];
  const void* xpw   = d_in[5];
  const void* dtw   = d_in[6];
  const void* dtb   = d_in[7];
  const void* alog  = d_in[8];
  const void* dpar  = d_in[9];
  const void* outw  = d_in[10];
  const void* normw = d_in[11];
  const void* normf = d_in[12];

  // workspace layout (~132 MB), all chunks 16B-aligned
  char* p = (char*)d_ws;
  int*    flag = (int*)p;    p += 16;
  float*  res  = (float*)p;  p += (size_t)BLL * DMODEL * 4;        // fp32 residual
  ushort* h    = (ushort*)p; p += (size_t)BLL * DMODEL * 2;        // rms out (bf16)
  float*  xz   = (float*)p;  p += (size_t)BLL * 2 * DINNER * 4;    // in_proj out [xi|z] fp32
  ushort* xcb  = (ushort*)p; p += (size_t)BLL * DINNER * 2;        // conv+silu out bf16
  float*  xcf  = (float*)p;  p += (size_t)BLL * DINNER * 4;        // conv+silu out fp32
  float*  dbl  = (float*)p;  p += (size_t)BLL * 80 * 4;            // x_proj out
  float*  dt   = (float*)p;  p += (size_t)BLL * DINNER * 4;        // softplus dt
  ushort* yg   = (ushort*)p; p += (size_t)BLL * DINNER * 2;        // gated scan out bf16
  ushort* inwb = (ushort*)p; p += (size_t)NLAYER * 2 * DINNER * DMODEL * 2;
  ushort* xpwb = (ushort*)p; p += (size_t)NLAYER * 80 * DINNER * 2;
  ushort* outwb= (ushort*)p; p += (size_t)NLAYER * DMODEL * DINNER * 2;

  probe_kernel<<<1, 256, 0, stream>>>(emb, flag);
  wcvt_kernel<<<(NLAYER * 2 * DINNER * DMODEL) / 256, 256, 0, stream>>>(inw, 0, inwb, flag);
  wcvt_kernel<<<(NLAYER * 80 * DINNER) / 256, 256, 0, stream>>>(xpw, 0, xpwb, flag);
  wcvt_kernel<<<(NLAYER * DMODEL * DINNER) / 256, 256, 0, stream>>>(outw, 0, outwb, flag);

  embed_kernel<<<BLL * DMODEL / 256, 256, 0, stream>>>(ids, emb, res, flag);

  for (int i = 0; i < NLAYER; ++i) {
    rms_kernel<<<BLL, 256, 0, stream>>>(res, normw, (size_t)i * DMODEL, h, flag, 0);
    gemm_nt<0><<<dim3(2 * DINNER / 64, BLL / 64), 256, 0, stream>>>(
        h, inwb + (size_t)i * 2 * DINNER * DMODEL, xz, BLL, 2 * DINNER, DMODEL);
    conv_kernel<<<BLL * DINNER / 256, 256, 0, stream>>>(
        xz, cw, (size_t)i * DINNER * KCONV, cb, (size_t)i * DINNER, xcb, xcf, flag);
    gemm_nt<0><<<dim3(2, BLL / 64), 256, 0, stream>>>(
        xcb, xpwb + (size_t)i * 80 * DINNER, dbl, BLL, 80, DINNER);
    dtproj_kernel<<<BLL * DINNER / 256, 256, 0, stream>>>(
        dbl, dtw, (size_t)i * DINNER * RRANK, dtb, (size_t)i * DINNER, dt, flag);
    scan_kernel<<<BATCH * (DINNER / 16), 256, 0, stream>>>(
        dt, xcf, dbl, xz, alog, (size_t)i * DINNER * NSTATE, dpar, (size_t)i * DINNER,
        yg, flag);
    gemm_nt<2><<<dim3(DMODEL / 64, BLL / 64), 256, 0, stream>>>(
        yg, outwb + (size_t)i * DMODEL * DINNER, res, BLL, DMODEL, DINNER);
  }

  rms_kernel<<<BLL, 256, 0, stream>>>(res, normf, 0, d_out, flag, 1);
}

// Round 3
// 5906.664 us; speedup vs baseline: 1.8249x; 1.8249x over previous
//
#include <hip/hip_runtime.h>
#include <stdint.h>

#define DMODEL 768
#define DINNER 1536
#define NSTATE 16
#define KCONV 4
#define RRANK 48
#define NLAYER 8
#define BLL 2048   // B*L tokens
#define LSEQ 1024
#define BATCH 2
#define NCHUNK 16
#define CLEN 64    // LSEQ / NCHUNK

__device__ __forceinline__ float bf2f(ushort u) {
  union { float f; uint32_t i; } v; v.i = ((uint32_t)u) << 16; return v.f;
}
__device__ __forceinline__ ushort f2bf(float f) {
  uint32_t x = __float_as_uint(f);
  uint32_t r = (x + 0x7fffu + ((x >> 16) & 1u)) >> 16;  // round-nearest-even
  return (ushort)r;
}
// flag-switched input loader: fp32flag=1 -> fp32 data, 0 -> bf16 data
__device__ __forceinline__ float ldf(const void* p, size_t i, int fp32flag) {
  return fp32flag ? ((const float*)p)[i] : bf2f(((const ushort*)p)[i]);
}

typedef __attribute__((ext_vector_type(8))) __bf16 bf16x8;
typedef __attribute__((ext_vector_type(4))) float f32x4;

// ---------------- dtype probe: is input data fp32 or bf16? ----------------
__global__ __launch_bounds__(256) void probe_kernel(const void* emb, int* flag) {
  int tid = threadIdx.x;
  int good = 0;
  for (int i = tid; i < 4096; i += 256) {
    float v = bf2f(((const ushort*)emb)[2 * i]);  // little-endian low half
    float a = fabsf(v);
    if (v == 0.f || (a >= 1e-8f && a <= 1e4f)) good++;
  }
  __shared__ int red[4];
  #pragma unroll
  for (int off = 32; off > 0; off >>= 1) good += __shfl_down(good, off, 64);
  if ((tid & 63) == 0) red[tid >> 6] = good;
  __syncthreads();
  if (tid == 0) {
    int g = red[0] + red[1] + red[2] + red[3];
    *flag = (g < 2867) ? 1 : 0;   // <70% sane => fp32 inputs
  }
}

// ---------------- weight convert: input (either dtype) -> bf16 ws copy ----------------
__global__ __launch_bounds__(256) void wcvt_kernel(const void* src, size_t elem_off,
                                                   ushort* __restrict__ dst,
                                                   const int* __restrict__ flag) {
  int f = *flag;
  size_t i = (size_t)blockIdx.x * 256 + threadIdx.x;
  dst[i] = f2bf(ldf(src, elem_off + i, f));
}

// ---------------- embedding lookup -> fp32 residual ----------------
__global__ __launch_bounds__(256) void embed_kernel(
    const int* __restrict__ ids, const void* __restrict__ emb,
    float* __restrict__ res, const int* __restrict__ flag) {
  int f = *flag;
  int idx = blockIdx.x * 256 + threadIdx.x;           // BLL*DMODEL
  int m = idx / DMODEL, c = idx % DMODEL;
  res[idx] = ldf(emb, (size_t)ids[m] * DMODEL + c, f);
}

// ---------------- RMSNorm: res(f32) -> h(bf16) or final out (per flag) ----------------
__global__ __launch_bounds__(256) void rms_kernel(
    const float* __restrict__ res, const void* __restrict__ w, size_t w_off,
    void* __restrict__ out, const int* __restrict__ flag, int final_store) {
  int f = *flag;
  int m = blockIdx.x;
  const float* r = res + (size_t)m * DMODEL;
  float ss = 0.f;
  for (int i = threadIdx.x; i < DMODEL; i += 256) { float v = r[i]; ss += v * v; }
  #pragma unroll
  for (int off = 32; off > 0; off >>= 1) ss += __shfl_down(ss, off, 64);
  __shared__ float red[4];
  if ((threadIdx.x & 63) == 0) red[threadIdx.x >> 6] = ss;
  __syncthreads();
  float scale = rsqrtf((red[0] + red[1] + red[2] + red[3]) / (float)DMODEL + 1e-5f);
  for (int i = threadIdx.x; i < DMODEL; i += 256) {
    float v = r[i] * scale * ldf(w, w_off + i, f);
    size_t o = (size_t)m * DMODEL + i;
    if (final_store) {
      if (f) ((float*)out)[o] = v; else ((ushort*)out)[o] = f2bf(v);
    } else {
      ((ushort*)out)[o] = f2bf(v);
    }
  }
}

// ---------------- GEMM: C[M,N] (+)= A[M,K] * W[N,K]^T ----------------
template <int OUT_MODE>  // 0 = f32 store, 2 = f32 accumulate
__global__ __launch_bounds__(256) void gemm_nt(
    const ushort* __restrict__ A, const ushort* __restrict__ W,
    float* __restrict__ Cout, int M, int N, int K) {
  int wave = threadIdx.x >> 6, lane = threadIdx.x & 63;
  int quad = lane >> 4, lq = lane & 15;
  int bm = blockIdx.y * 64, bn = blockIdx.x * 64;
  int row = bm + wave * 16 + lq;
  const ushort* Ap = A + (size_t)row * K + quad * 8;
  f32x4 acc[4] = {};
  for (int kk = 0; kk < K; kk += 32) {
    bf16x8 af = *(const bf16x8*)(Ap + kk);
    #pragma unroll
    for (int t = 0; t < 4; ++t) {
      int col = bn + t * 16 + lq;
      bf16x8 bfv = {};
      if (col < N) bfv = *(const bf16x8*)(W + (size_t)col * K + kk + quad * 8);
      acc[t] = __builtin_amdgcn_mfma_f32_16x16x32_bf16(af, bfv, acc[t], 0, 0, 0);
    }
  }
  #pragma unroll
  for (int t = 0; t < 4; ++t) {
    int col = bn + t * 16 + lq;
    if (col >= N) continue;
    #pragma unroll
    for (int r = 0; r < 4; ++r) {
      int rr = bm + wave * 16 + quad * 4 + r;
      size_t off = (size_t)rr * N + col;
      if (OUT_MODE == 0) Cout[off] = acc[t][r];
      else               Cout[off] += acc[t][r];
    }
  }
}

// ---------------- causal depthwise conv (K=4) + SiLU ----------------
__global__ __launch_bounds__(256) void conv_kernel(
    const float* __restrict__ xz, const void* __restrict__ cw, size_t cw_off,
    const void* __restrict__ cb, size_t cb_off,
    ushort* __restrict__ xcb, float* __restrict__ xcf,
    const int* __restrict__ flag) {
  int f = *flag;
  int idx = blockIdx.x * 256 + threadIdx.x;           // BLL*DINNER
  int d = idx % DINNER, m = idx / DINNER;
  int l = m & (LSEQ - 1);
  float s = ldf(cb, cb_off + d, f);
  #pragma unroll
  for (int k = 0; k < KCONV; ++k) {
    int ls = l - (KCONV - 1) + k;
    if (ls >= 0)
      s = fmaf(xz[(size_t)(m - (KCONV - 1) + k) * (2 * DINNER) + d],
               ldf(cw, cw_off + d * KCONV + k, f), s);
  }
  float v = s / (1.f + __expf(-s));   // silu
  xcb[idx] = f2bf(v);
  xcf[idx] = v;
}

// ---------------- dt = softplus(dt_raw @ dt_proj_w^T + dt_proj_b) ----------------
__global__ __launch_bounds__(256) void dtproj_kernel(
    const float* __restrict__ dbl, const void* __restrict__ dtw, size_t dtw_off,
    const void* __restrict__ dtb, size_t dtb_off,
    float* __restrict__ dt, const int* __restrict__ flag) {
  int f = *flag;
  int idx = blockIdx.x * 256 + threadIdx.x;           // BLL*DINNER
  int d = idx % DINNER, m = idx / DINNER;
  const float* rowp = dbl + (size_t)m * 80;
  float s = ldf(dtb, dtb_off + d, f);
  #pragma unroll 8
  for (int r = 0; r < RRANK; ++r)
    s = fmaf(rowp[r], ldf(dtw, dtw_off + (size_t)d * RRANK + r, f), s);
  dt[idx] = (s > 20.f) ? s : log1pf(__expf(s));
}

// ============ chunk-parallel selective scan ============
// h[l] = a[l]*h[l-1] + b[l]; L split into NCHUNK chunks of CLEN.
// P1: per (b, dblk, chunk) block, thread (d_local, n): chunk-local scan from 0
//     -> carryP = prod(a), carryH = partial h at chunk end.
__global__ __launch_bounds__(256) void scan_p1(
    const float* __restrict__ dt, const float* __restrict__ xcf,
    const float* __restrict__ dbl,
    const void* __restrict__ A_log, size_t al_off,
    float* __restrict__ carryP, float* __restrict__ carryH,
    const int* __restrict__ flag) {
  int f = *flag;
  int chunk = blockIdx.x % NCHUNK;
  int dblk  = (blockIdx.x / NCHUNK) % (DINNER / 16);
  int b     =  blockIdx.x / (NCHUNK * (DINNER / 16));
  int n = threadIdx.x & 15;
  int d = dblk * 16 + (threadIdx.x >> 4);
  float Ac = -__expf(ldf(A_log, al_off + (size_t)d * NSTATE + n, f));
  float h = 0.f, P = 1.f;
  int l0 = chunk * CLEN;
  for (int l = l0; l < l0 + CLEN; ++l) {
    size_t m = (size_t)b * LSEQ + l;
    float dtv = dt[m * DINNER + d];
    float u   = xcf[m * DINNER + d];
    float Bv  = dbl[m * 80 + 48 + n];
    float a = __expf(dtv * Ac);
    h = fmaf(a, h, dtv * u * Bv);
    P *= a;
  }
  size_t ci = (((size_t)b * NCHUNK + chunk) * DINNER + d) * 16 + n;
  carryP[ci] = P;
  carryH[ci] = h;
}

// P2: sequential carry combine over chunks; one thread per (b,d,n).
__global__ __launch_bounds__(256) void scan_p2(
    const float* __restrict__ carryP, const float* __restrict__ carryH,
    float* __restrict__ hin) {
  int idx = blockIdx.x * 256 + threadIdx.x;          // BATCH*DINNER*16
  int n = idx & 15;
  int d = (idx >> 4) % DINNER;
  int b = idx / (16 * DINNER);
  float h = 0.f;
  for (int c = 0; c < NCHUNK; ++c) {
    size_t ci = (((size_t)b * NCHUNK + c) * DINNER + d) * 16 + n;
    hin[ci] = h;
    h = fmaf(carryP[ci], h, carryH[ci]);
  }
}

// P3: re-run true recurrence from hin; fused n-reduce + D skip + silu(z) gate.
__global__ __launch_bounds__(256) void scan_p3(
    const float* __restrict__ dt, const float* __restrict__ xcf,
    const float* __restrict__ dbl, const float* __restrict__ xz,
    const void* __restrict__ A_log, size_t al_off,
    const void* __restrict__ Dp, size_t dp_off,
    const float* __restrict__ hin, ushort* __restrict__ yg,
    const int* __restrict__ flag) {
  int f = *flag;
  int chunk = blockIdx.x % NCHUNK;
  int dblk  = (blockIdx.x / NCHUNK) % (DINNER / 16);
  int b     =  blockIdx.x / (NCHUNK * (DINNER / 16));
  int n = threadIdx.x & 15;
  int d = dblk * 16 + (threadIdx.x >> 4);
  float Ac = -__expf(ldf(A_log, al_off + (size_t)d * NSTATE + n, f));
  float Dd = ldf(Dp, dp_off + d, f);
  float h = hin[(((size_t)b * NCHUNK + chunk) * DINNER + d) * 16 + n];
  int l0 = chunk * CLEN;
  for (int l = l0; l < l0 + CLEN; ++l) {
    size_t m = (size_t)b * LSEQ + l;
    float dtv = dt[m * DINNER + d];
    float u   = xcf[m * DINNER + d];
    float Bv  = dbl[m * 80 + 48 + n];
    float Cv  = dbl[m * 80 + 64 + n];
    float a = __expf(dtv * Ac);
    h = fmaf(a, h, dtv * u * Bv);
    float p = h * Cv;
    p += __shfl_xor(p, 8, 16);
    p += __shfl_xor(p, 4, 16);
    p += __shfl_xor(p, 2, 16);
    p += __shfl_xor(p, 1, 16);
    if (n == 0) {
      float y = p + u * Dd;
      float zv = xz[m * (2 * DINNER) + DINNER + d];
      float g = zv / (1.f + __expf(-zv));             // silu(z)
      yg[m * DINNER + d] = f2bf(y * g);
    }
  }
}

extern "C" void kernel_launch(void* const* d_in, const int* in_sizes, int n_in,
                              void* d_out, int out_size, void* d_ws, size_t ws_size,
                              hipStream_t stream) {
  const int*  ids   = (const int*)d_in[0];
  const void* emb   = d_in[1];
  const void* inw   = d_in[2];
  const void* cw    = d_in[3];
  const void* cb    = d_in[4];
  const void* xpw   = d_in[5];
  const void* dtw   = d_in[6];
  const void* dtb   = d_in[7];
  const void* alog  = d_in[8];
  const void* dpar  = d_in[9];
  const void* outw  = d_in[10];
  const void* normw = d_in[11];
  const void* normf = d_in[12];

  // workspace layout, all chunks 16B-aligned
  char* p = (char*)d_ws;
  int*    flag = (int*)p;    p += 16;
  float*  res  = (float*)p;  p += (size_t)BLL * DMODEL * 4;
  ushort* h    = (ushort*)p; p += (size_t)BLL * DMODEL * 2;
  float*  xz   = (float*)p;  p += (size_t)BLL * 2 * DINNER * 4;
  ushort* xcb  = (ushort*)p; p += (size_t)BLL * DINNER * 2;
  float*  xcf  = (float*)p;  p += (size_t)BLL * DINNER * 4;
  float*  dbl  = (float*)p;  p += (size_t)BLL * 80 * 4;
  float*  dt   = (float*)p;  p += (size_t)BLL * DINNER * 4;
  ushort* yg   = (ushort*)p; p += (size_t)BLL * DINNER * 2;
  float*  carryP = (float*)p; p += (size_t)BATCH * NCHUNK * DINNER * 16 * 4;
  float*  carryH = (float*)p; p += (size_t)BATCH * NCHUNK * DINNER * 16 * 4;
  float*  hin    = (float*)p; p += (size_t)BATCH * NCHUNK * DINNER * 16 * 4;
  ushort* inwb = (ushort*)p; p += (size_t)NLAYER * 2 * DINNER * DMODEL * 2;
  ushort* xpwb = (ushort*)p; p += (size_t)NLAYER * 80 * DINNER * 2;
  ushort* outwb= (ushort*)p; p += (size_t)NLAYER * DMODEL * DINNER * 2;

  probe_kernel<<<1, 256, 0, stream>>>(emb, flag);
  wcvt_kernel<<<(NLAYER * 2 * DINNER * DMODEL) / 256, 256, 0, stream>>>(inw, 0, inwb, flag);
  wcvt_kernel<<<(NLAYER * 80 * DINNER) / 256, 256, 0, stream>>>(xpw, 0, xpwb, flag);
  wcvt_kernel<<<(NLAYER * DMODEL * DINNER) / 256, 256, 0, stream>>>(outw, 0, outwb, flag);

  embed_kernel<<<BLL * DMODEL / 256, 256, 0, stream>>>(ids, emb, res, flag);

  const int scan_grid = BATCH * (DINNER / 16) * NCHUNK;   // 3072
  for (int i = 0; i < NLAYER; ++i) {
    rms_kernel<<<BLL, 256, 0, stream>>>(res, normw, (size_t)i * DMODEL, h, flag, 0);
    gemm_nt<0><<<dim3(2 * DINNER / 64, BLL / 64), 256, 0, stream>>>(
        h, inwb + (size_t)i * 2 * DINNER * DMODEL, xz, BLL, 2 * DINNER, DMODEL);
    conv_kernel<<<BLL * DINNER / 256, 256, 0, stream>>>(
        xz, cw, (size_t)i * DINNER * KCONV, cb, (size_t)i * DINNER, xcb, xcf, flag);
    gemm_nt<0><<<dim3(2, BLL / 64), 256, 0, stream>>>(
        xcb, xpwb + (size_t)i * 80 * DINNER, dbl, BLL, 80, DINNER);
    dtproj_kernel<<<BLL * DINNER / 256, 256, 0, stream>>>(
        dbl, dtw, (size_t)i * DINNER * RRANK, dtb, (size_t)i * DINNER, dt, flag);
    scan_p1<<<scan_grid, 256, 0, stream>>>(
        dt, xcf, dbl, alog, (size_t)i * DINNER * NSTATE, carryP, carryH, flag);
    scan_p2<<<BATCH * DINNER * 16 / 256, 256, 0, stream>>>(carryP, carryH, hin);
    scan_p3<<<scan_grid, 256, 0, stream>>>(
        dt, xcf, dbl, xz, alog, (size_t)i * DINNER * NSTATE, dpar, (size_t)i * DINNER,
        hin, yg, flag);
    gemm_nt<2><<<dim3(DMODEL / 64, BLL / 64), 256, 0, stream>>>(
        yg, outwb + (size_t)i * DMODEL * DINNER, res, BLL, DMODEL, DINNER);
  }

  rms_kernel<<<BLL, 256, 0, stream>>>(res, normf, 0, d_out, flag, 1);
}

// Round 4
// 3391.677 us; speedup vs baseline: 3.1781x; 1.7415x over previous
//
#include <hip/hip_runtime.h>
#include <stdint.h>

#define DMODEL 768
#define DINNER 1536
#define NSTATE 16
#define KCONV 4
#define RRANK 48
#define NLAYER 8
#define BLL 2048   // B*L tokens
#define LSEQ 1024
#define BATCH 2
#define NCHUNK 16
#define CLEN 64    // LSEQ / NCHUNK

__device__ __forceinline__ float bf2f(ushort u) {
  union { float f; uint32_t i; } v; v.i = ((uint32_t)u) << 16; return v.f;
}
__device__ __forceinline__ ushort f2bf(float f) {
  uint32_t x = __float_as_uint(f);
  uint32_t r = (x + 0x7fffu + ((x >> 16) & 1u)) >> 16;  // round-nearest-even
  return (ushort)r;
}
// flag-switched input loader: fp32flag=1 -> fp32 data, 0 -> bf16 data
__device__ __forceinline__ float ldf(const void* p, size_t i, int fp32flag) {
  return fp32flag ? ((const float*)p)[i] : bf2f(((const ushort*)p)[i]);
}

typedef __attribute__((ext_vector_type(8))) __bf16 bf16x8;
typedef __attribute__((ext_vector_type(4))) float f32x4;

// ---------------- dtype probe: is input data fp32 or bf16? ----------------
__global__ __launch_bounds__(256) void probe_kernel(const void* emb, int* flag) {
  int tid = threadIdx.x;
  int good = 0;
  for (int i = tid; i < 4096; i += 256) {
    float v = bf2f(((const ushort*)emb)[2 * i]);  // little-endian low half
    float a = fabsf(v);
    if (v == 0.f || (a >= 1e-8f && a <= 1e4f)) good++;
  }
  __shared__ int red[4];
  #pragma unroll
  for (int off = 32; off > 0; off >>= 1) good += __shfl_down(good, off, 64);
  if ((tid & 63) == 0) red[tid >> 6] = good;
  __syncthreads();
  if (tid == 0) {
    int g = red[0] + red[1] + red[2] + red[3];
    *flag = (g < 2867) ? 1 : 0;   // <70% sane => fp32 inputs
  }
}

// ---------------- weight convert: input (either dtype) -> bf16 ws copy ----------------
__global__ __launch_bounds__(256) void wcvt_kernel(const void* src, size_t elem_off,
                                                   ushort* __restrict__ dst,
                                                   const int* __restrict__ flag) {
  int f = *flag;
  size_t i = (size_t)blockIdx.x * 256 + threadIdx.x;
  dst[i] = f2bf(ldf(src, elem_off + i, f));
}

// ---------------- dt_proj_w transpose: [l][d][r] -> [l][r][d], fp32 ----------------
__global__ __launch_bounds__(256) void dtwT_kernel(const void* dtw, float* __restrict__ dtwT,
                                                   const int* __restrict__ flag) {
  int f = *flag;
  size_t i = (size_t)blockIdx.x * 256 + threadIdx.x;   // NLAYER*RRANK*DINNER
  int d = i % DINNER;
  int r = (i / DINNER) % RRANK;
  int l = i / (DINNER * RRANK);
  dtwT[i] = ldf(dtw, ((size_t)l * DINNER + d) * RRANK + r, f);
}

// ---------------- embedding lookup -> fp32 residual ----------------
__global__ __launch_bounds__(256) void embed_kernel(
    const int* __restrict__ ids, const void* __restrict__ emb,
    float* __restrict__ res, const int* __restrict__ flag) {
  int f = *flag;
  int idx = blockIdx.x * 256 + threadIdx.x;           // BLL*DMODEL
  int m = idx / DMODEL, c = idx % DMODEL;
  res[idx] = ldf(emb, (size_t)ids[m] * DMODEL + c, f);
}

// ---------------- RMSNorm: res(f32) -> h(bf16) or final out (per flag) ----------------
__global__ __launch_bounds__(256) void rms_kernel(
    const float* __restrict__ res, const void* __restrict__ w, size_t w_off,
    void* __restrict__ out, const int* __restrict__ flag, int final_store) {
  int f = *flag;
  int m = blockIdx.x;
  const float* r = res + (size_t)m * DMODEL;
  float ss = 0.f;
  for (int i = threadIdx.x; i < DMODEL; i += 256) { float v = r[i]; ss += v * v; }
  #pragma unroll
  for (int off = 32; off > 0; off >>= 1) ss += __shfl_down(ss, off, 64);
  __shared__ float red[4];
  if ((threadIdx.x & 63) == 0) red[threadIdx.x >> 6] = ss;
  __syncthreads();
  float scale = rsqrtf((red[0] + red[1] + red[2] + red[3]) / (float)DMODEL + 1e-5f);
  for (int i = threadIdx.x; i < DMODEL; i += 256) {
    float v = r[i] * scale * ldf(w, w_off + i, f);
    size_t o = (size_t)m * DMODEL + i;
    if (final_store) {
      if (f) ((float*)out)[o] = v; else ((ushort*)out)[o] = f2bf(v);
    } else {
      ((ushort*)out)[o] = f2bf(v);
    }
  }
}

// ---------------- GEMM: C[M,N] (+)= A[M,K] * W[N,K]^T ----------------
template <int OUT_MODE>  // 0 = f32 store, 2 = f32 accumulate
__global__ __launch_bounds__(256) void gemm_nt(
    const ushort* __restrict__ A, const ushort* __restrict__ W,
    float* __restrict__ Cout, int M, int N, int K) {
  int wave = threadIdx.x >> 6, lane = threadIdx.x & 63;
  int quad = lane >> 4, lq = lane & 15;
  int bm = blockIdx.y * 64, bn = blockIdx.x * 64;
  int row = bm + wave * 16 + lq;
  const ushort* Ap = A + (size_t)row * K + quad * 8;
  f32x4 acc[4] = {};
  for (int kk = 0; kk < K; kk += 32) {
    bf16x8 af = *(const bf16x8*)(Ap + kk);
    #pragma unroll
    for (int t = 0; t < 4; ++t) {
      int col = bn + t * 16 + lq;
      bf16x8 bfv = {};
      if (col < N) bfv = *(const bf16x8*)(W + (size_t)col * K + kk + quad * 8);
      acc[t] = __builtin_amdgcn_mfma_f32_16x16x32_bf16(af, bfv, acc[t], 0, 0, 0);
    }
  }
  #pragma unroll
  for (int t = 0; t < 4; ++t) {
    int col = bn + t * 16 + lq;
    if (col >= N) continue;
    #pragma unroll
    for (int r = 0; r < 4; ++r) {
      int rr = bm + wave * 16 + quad * 4 + r;
      size_t off = (size_t)rr * N + col;
      if (OUT_MODE == 0) Cout[off] = acc[t][r];
      else               Cout[off] += acc[t][r];
    }
  }
}

// ---------------- causal depthwise conv (K=4) + SiLU ----------------
__global__ __launch_bounds__(256) void conv_kernel(
    const float* __restrict__ xz, const void* __restrict__ cw, size_t cw_off,
    const void* __restrict__ cb, size_t cb_off,
    ushort* __restrict__ xcb, float* __restrict__ xcf,
    const int* __restrict__ flag) {
  int f = *flag;
  int idx = blockIdx.x * 256 + threadIdx.x;           // BLL*DINNER
  int d = idx % DINNER, m = idx / DINNER;
  int l = m & (LSEQ - 1);
  float s = ldf(cb, cb_off + d, f);
  #pragma unroll
  for (int k = 0; k < KCONV; ++k) {
    int ls = l - (KCONV - 1) + k;
    if (ls >= 0)
      s = fmaf(xz[(size_t)(m - (KCONV - 1) + k) * (2 * DINNER) + d],
               ldf(cw, cw_off + d * KCONV + k, f), s);
  }
  float v = s / (1.f + __expf(-s));   // silu
  xcb[idx] = f2bf(v);
  xcf[idx] = v;
}

// ---------------- dt = softplus(dt_raw @ dt_proj_w^T + dt_proj_b) ----------------
// dtwT is [r][DINNER] fp32 (transposed, per layer) -> coalesced lane reads.
__global__ __launch_bounds__(256) void dtproj_kernel(
    const float* __restrict__ dbl, const float* __restrict__ dtwT,
    const void* __restrict__ dtb, size_t dtb_off,
    float* __restrict__ dt, const int* __restrict__ flag) {
  int f = *flag;
  int idx = blockIdx.x * 256 + threadIdx.x;           // BLL*DINNER
  int d = idx % DINNER, m = idx / DINNER;
  const float* rowp = dbl + (size_t)m * 80;
  float s = ldf(dtb, dtb_off + d, f);
  #pragma unroll 8
  for (int r = 0; r < RRANK; ++r)
    s = fmaf(rowp[r], dtwT[(size_t)r * DINNER + d], s);
  dt[idx] = (s > 20.f) ? s : log1pf(__expf(s));
}

// ============ chunk-parallel selective scan ============
// P1: chunk-local scan from 0 -> carryP = prod(a), carryH = partial h.
__global__ __launch_bounds__(256) void scan_p1(
    const float* __restrict__ dt, const float* __restrict__ xcf,
    const float* __restrict__ dbl,
    const void* __restrict__ A_log, size_t al_off,
    float* __restrict__ carryP, float* __restrict__ carryH,
    const int* __restrict__ flag) {
  int f = *flag;
  int chunk = blockIdx.x % NCHUNK;
  int dblk  = (blockIdx.x / NCHUNK) % (DINNER / 16);
  int b     =  blockIdx.x / (NCHUNK * (DINNER / 16));
  int n = threadIdx.x & 15;
  int d = dblk * 16 + (threadIdx.x >> 4);
  float Ac = -__expf(ldf(A_log, al_off + (size_t)d * NSTATE + n, f));
  float h = 0.f, P = 1.f;
  int l0 = chunk * CLEN;
  for (int l = l0; l < l0 + CLEN; ++l) {
    size_t m = (size_t)b * LSEQ + l;
    float dtv = dt[m * DINNER + d];
    float u   = xcf[m * DINNER + d];
    float Bv  = dbl[m * 80 + 48 + n];
    float a = __expf(dtv * Ac);
    h = fmaf(a, h, dtv * u * Bv);
    P *= a;
  }
  size_t ci = (((size_t)b * NCHUNK + chunk) * DINNER + d) * 16 + n;
  carryP[ci] = P;
  carryH[ci] = h;
}

// P2: sequential carry combine over chunks; one thread per (b,d,n).
__global__ __launch_bounds__(256) void scan_p2(
    const float* __restrict__ carryP, const float* __restrict__ carryH,
    float* __restrict__ hin) {
  int idx = blockIdx.x * 256 + threadIdx.x;          // BATCH*DINNER*16
  int n = idx & 15;
  int d = (idx >> 4) % DINNER;
  int b = idx / (16 * DINNER);
  float h = 0.f;
  for (int c = 0; c < NCHUNK; ++c) {
    size_t ci = (((size_t)b * NCHUNK + c) * DINNER + d) * 16 + n;
    hin[ci] = h;
    h = fmaf(carryP[ci], h, carryH[ci]);
  }
}

// P3: re-run true recurrence from hin; fused n-reduce + D skip + silu(z) gate.
__global__ __launch_bounds__(256) void scan_p3(
    const float* __restrict__ dt, const float* __restrict__ xcf,
    const float* __restrict__ dbl, const float* __restrict__ xz,
    const void* __restrict__ A_log, size_t al_off,
    const void* __restrict__ Dp, size_t dp_off,
    const float* __restrict__ hin, ushort* __restrict__ yg,
    const int* __restrict__ flag) {
  int f = *flag;
  int chunk = blockIdx.x % NCHUNK;
  int dblk  = (blockIdx.x / NCHUNK) % (DINNER / 16);
  int b     =  blockIdx.x / (NCHUNK * (DINNER / 16));
  int n = threadIdx.x & 15;
  int d = dblk * 16 + (threadIdx.x >> 4);
  float Ac = -__expf(ldf(A_log, al_off + (size_t)d * NSTATE + n, f));
  float Dd = ldf(Dp, dp_off + d, f);
  float h = hin[(((size_t)b * NCHUNK + chunk) * DINNER + d) * 16 + n];
  int l0 = chunk * CLEN;
  for (int l = l0; l < l0 + CLEN; ++l) {
    size_t m = (size_t)b * LSEQ + l;
    float dtv = dt[m * DINNER + d];
    float u   = xcf[m * DINNER + d];
    float Bv  = dbl[m * 80 + 48 + n];
    float Cv  = dbl[m * 80 + 64 + n];
    float a = __expf(dtv * Ac);
    h = fmaf(a, h, dtv * u * Bv);
    float p = h * Cv;
    p += __shfl_xor(p, 8, 16);
    p += __shfl_xor(p, 4, 16);
    p += __shfl_xor(p, 2, 16);
    p += __shfl_xor(p, 1, 16);
    if (n == 0) {
      float y = p + u * Dd;
      float zv = xz[m * (2 * DINNER) + DINNER + d];
      float g = zv / (1.f + __expf(-zv));             // silu(z)
      yg[m * DINNER + d] = f2bf(y * g);
    }
  }
}

extern "C" void kernel_launch(void* const* d_in, const int* in_sizes, int n_in,
                              void* d_out, int out_size, void* d_ws, size_t ws_size,
                              hipStream_t stream) {
  const int*  ids   = (const int*)d_in[0];
  const void* emb   = d_in[1];
  const void* inw   = d_in[2];
  const void* cw    = d_in[3];
  const void* cb    = d_in[4];
  const void* xpw   = d_in[5];
  const void* dtw   = d_in[6];
  const void* dtb   = d_in[7];
  const void* alog  = d_in[8];
  const void* dpar  = d_in[9];
  const void* outw  = d_in[10];
  const void* normw = d_in[11];
  const void* normf = d_in[12];

  // workspace layout, all chunks 16B-aligned
  char* p = (char*)d_ws;
  int*    flag = (int*)p;    p += 16;
  float*  res  = (float*)p;  p += (size_t)BLL * DMODEL * 4;
  ushort* h    = (ushort*)p; p += (size_t)BLL * DMODEL * 2;
  float*  xz   = (float*)p;  p += (size_t)BLL * 2 * DINNER * 4;
  ushort* xcb  = (ushort*)p; p += (size_t)BLL * DINNER * 2;
  float*  xcf  = (float*)p;  p += (size_t)BLL * DINNER * 4;
  float*  dbl  = (float*)p;  p += (size_t)BLL * 80 * 4;
  float*  dt   = (float*)p;  p += (size_t)BLL * DINNER * 4;
  ushort* yg   = (ushort*)p; p += (size_t)BLL * DINNER * 2;
  float*  carryP = (float*)p; p += (size_t)BATCH * NCHUNK * DINNER * 16 * 4;
  float*  carryH = (float*)p; p += (size_t)BATCH * NCHUNK * DINNER * 16 * 4;
  float*  hin    = (float*)p; p += (size_t)BATCH * NCHUNK * DINNER * 16 * 4;
  float*  dtwT = (float*)p;  p += (size_t)NLAYER * RRANK * DINNER * 4;
  ushort* inwb = (ushort*)p; p += (size_t)NLAYER * 2 * DINNER * DMODEL * 2;
  ushort* xpwb = (ushort*)p; p += (size_t)NLAYER * 80 * DINNER * 2;
  ushort* outwb= (ushort*)p; p += (size_t)NLAYER * DMODEL * DINNER * 2;

  probe_kernel<<<1, 256, 0, stream>>>(emb, flag);
  wcvt_kernel<<<(NLAYER * 2 * DINNER * DMODEL) / 256, 256, 0, stream>>>(inw, 0, inwb, flag);
  wcvt_kernel<<<(NLAYER * 80 * DINNER) / 256, 256, 0, stream>>>(xpw, 0, xpwb, flag);
  wcvt_kernel<<<(NLAYER * DMODEL * DINNER) / 256, 256, 0, stream>>>(outw, 0, outwb, flag);
  dtwT_kernel<<<(NLAYER * RRANK * DINNER) / 256, 256, 0, stream>>>(dtw, dtwT, flag);

  embed_kernel<<<BLL * DMODEL / 256, 256, 0, stream>>>(ids, emb, res, flag);

  const int scan_grid = BATCH * (DINNER / 16) * NCHUNK;   // 3072
  for (int i = 0; i < NLAYER; ++i) {
    rms_kernel<<<BLL, 256, 0, stream>>>(res, normw, (size_t)i * DMODEL, h, flag, 0);
    gemm_nt<0><<<dim3(2 * DINNER / 64, BLL / 64), 256, 0, stream>>>(
        h, inwb + (size_t)i * 2 * DINNER * DMODEL, xz, BLL, 2 * DINNER, DMODEL);
    conv_kernel<<<BLL * DINNER / 256, 256, 0, stream>>>(
        xz, cw, (size_t)i * DINNER * KCONV, cb, (size_t)i * DINNER, xcb, xcf, flag);
    gemm_nt<0><<<dim3(2, BLL / 64), 256, 0, stream>>>(
        xcb, xpwb + (size_t)i * 80 * DINNER, dbl, BLL, 80, DINNER);
    dtproj_kernel<<<BLL * DINNER / 256, 256, 0, stream>>>(
        dbl, dtwT + (size_t)i * RRANK * DINNER, dtb, (size_t)i * DINNER, dt, flag);
    scan_p1<<<scan_grid, 256, 0, stream>>>(
        dt, xcf, dbl, alog, (size_t)i * DINNER * NSTATE, carryP, carryH, flag);
    scan_p2<<<BATCH * DINNER * 16 / 256, 256, 0, stream>>>(carryP, carryH, hin);
    scan_p3<<<scan_grid, 256, 0, stream>>>(
        dt, xcf, dbl, xz, alog, (size_t)i * DINNER * NSTATE, dpar, (size_t)i * DINNER,
        hin, yg, flag);
    gemm_nt<2><<<dim3(DMODEL / 64, BLL / 64), 256, 0, stream>>>(
        yg, outwb + (size_t)i * DMODEL * DINNER, res, BLL, DMODEL, DINNER);
  }

  rms_kernel<<<BLL, 256, 0, stream>>>(res, normf, 0, d_out, flag, 1);
}